// Round 2
// baseline (612.806 us; speedup 1.0000x reference)
//
#include <hip/hip_runtime.h>
#include <hip/hip_bf16.h>

#define N_NODES 100000
#define N_EDGES 600000
#define D 128
#define ROWS_PB 32                               // dst rows per bucket/block
#define NBUCK (N_NODES / ROWS_PB)                // 3125
#define CAP 448                                  // bucket capacity (mean 192, ~18 sigma headroom)
#define GSTR 132                                 // padded LDS row stride (floats)

typedef __attribute__((ext_vector_type(8))) short short8;
typedef __attribute__((ext_vector_type(8))) unsigned short ushort8;
typedef __attribute__((ext_vector_type(4))) float f32x4;

union V8 { short8 s8; ushort8 u8; };

__device__ __forceinline__ unsigned short f2bf(float f) {
    unsigned u = __float_as_uint(f);
    u += 0x7FFF + ((u >> 16) & 1);   // RNE
    return (unsigned short)(u >> 16);
}

// ---------------- weight fragments + cursor zeroing ----------------
__global__ void wfrag_kernel(const float* __restrict__ Wi,
                             const float* __restrict__ We,
                             unsigned short* __restrict__ Wfi,
                             unsigned short* __restrict__ Wfe,
                             unsigned* __restrict__ cur) {
    int id = blockIdx.x * blockDim.x + threadIdx.x;   // 0..4095
    if (id < NBUCK) cur[id] = 0u;                     // fold memset in
    int mat = id >> 11;
    int idx = id & 2047;          // nt<<8 | ks<<6 | lane
    int lane = idx & 63;
    int ks = (idx >> 6) & 3;
    int nt = idx >> 8;
    int n = lane & 15, quad = lane >> 4;
    int row = nt * 16 + n;
    int k0 = ks * 32 + quad * 8;
    const float* W = mat ? We : Wi;
    unsigned short* Wf = mat ? Wfe : Wfi;
    #pragma unroll
    for (int j = 0; j < 8; ++j)
        Wf[idx * 8 + j] = f2bf(W[row * D + k0 + j]);
}

// ---------------- one-pass bucket scatter (dst>>5 buckets) ----------------
// payload: int2{ (d&31)<<20 | s , bits(ew) } -- single 8B store per edge
__global__ void scatter_kernel(const int* __restrict__ src_idx,
                               const int* __restrict__ dst_idx,
                               const float* __restrict__ ew,
                               unsigned* __restrict__ cur,
                               int2* __restrict__ bkt) {
    int i = blockIdx.x * blockDim.x + threadIdx.x;
    if (i < N_EDGES) {
        int s = src_idx[i];
        int d = dst_idx[i];
        float wv = ew[i];
        int b = d >> 5;
        unsigned pos = atomicAdd(&cur[b], 1u);
        if (pos < CAP) {
            int2 m;
            m.x = ((d & 31) << 20) | s;
            m.y = __float_as_int(wv);
            bkt[(size_t)b * CAP + pos] = m;
        }
    }
}

// ---------------- fused gather-sum + dual GEMM + leaky ----------------
// out = leaky( (dst_x + g) @ Wi^T + (dst_x .* g) @ We^T ),
// g[d] = sum_{e: dst=d} ew_e * src_x[src_e]  (exact f32, in LDS).
// Phase 1: 16 quads stride the bucket's edges; per edge 8 LDS f32 atomics.
//          1-deep row pipeline (next row issued before current consumed);
//          OOB pad lanes carry weight 0 -> uniform control flow.
// Phase 2: W fragments loaded AFTER gather (laundered pointers + sched
//          barrier keep gather-phase register pressure low), then two
//          16-row MFMA tiles, leaky fused, out stored exactly once.
__global__ __launch_bounds__(256, 4) void fused_kernel(
    const float* __restrict__ src_x,
    const float* __restrict__ dst_x,
    const int2* __restrict__ bkt,
    const unsigned* __restrict__ cur,
    const unsigned short* __restrict__ Wfi,
    const unsigned short* __restrict__ Wfe,
    float* __restrict__ out) {
    __shared__ float g[ROWS_PB * GSTR];   // 32 x 132 f32 = 16.9 KB

    int t = threadIdx.x, lane = t & 63, w = t >> 6;
    int quad = lane >> 4, nl = lane & 15;
    int qid = t >> 4;                      // 0..15

    for (int i = t; i < ROWS_PB * GSTR; i += 256) g[i] = 0.f;
    __syncthreads();

    int b = blockIdx.x, d0 = b * ROWS_PB;
    int cnt = (int)cur[b];
    if (cnt > CAP) cnt = CAP;
    const int2* bk = bkt + (size_t)b * CAP;

    int iters = (cnt + 15) >> 4;
    if (iters > 0) {
        int2 m0 = (qid < cnt) ? bk[qid] : make_int2(0, 0);
        int2 m1 = (qid + 16 < cnt) ? bk[qid + 16] : make_int2(0, 0);
        const float* rp = src_x + (size_t)(m0.x & 0xFFFFF) * D + nl * 8;
        float4 rA = *(const float4*)rp;
        float4 rB = *(const float4*)(rp + 4);
        for (int it = 0; it < iters; ++it) {
            // issue next row load (address ready from m1)
            const float* rpn = src_x + (size_t)(m1.x & 0xFFFFF) * D + nl * 8;
            float4 rnA = *(const float4*)rpn;
            float4 rnB = *(const float4*)(rpn + 4);
            // metadata two ahead
            int k2 = qid + (it + 2) * 16;
            int2 m2 = (k2 < cnt) ? bk[k2] : make_int2(0, 0);
            // consume current edge
            float wgt = __int_as_float(m0.y);
            int dl = m0.x >> 20;
            float* gp = &g[dl * GSTR + nl * 8];
            atomicAdd(gp + 0, wgt * rA.x);
            atomicAdd(gp + 1, wgt * rA.y);
            atomicAdd(gp + 2, wgt * rA.z);
            atomicAdd(gp + 3, wgt * rA.w);
            atomicAdd(gp + 4, wgt * rB.x);
            atomicAdd(gp + 5, wgt * rB.y);
            atomicAdd(gp + 6, wgt * rB.z);
            atomicAdd(gp + 7, wgt * rB.w);
            m0 = m1; m1 = m2; rA = rnA; rB = rnB;
        }
    }
    __syncthreads();

    // ---- phase 2: load W fragments late (keep gather reg pressure low) ----
    const unsigned short* Wfi_l = Wfi;
    const unsigned short* Wfe_l = Wfe;
    asm volatile("" : "+v"(Wfi_l), "+v"(Wfe_l));   // block hoisting above gather
    __builtin_amdgcn_sched_barrier(0);

    const short8* Wiv = (const short8*)Wfi_l;
    const short8* Wev = (const short8*)Wfe_l;
    short8 Bi[2][4], Be[2][4];
    #pragma unroll
    for (int ntl = 0; ntl < 2; ++ntl)
        #pragma unroll
        for (int ks = 0; ks < 4; ++ks) {
            Bi[ntl][ks] = Wiv[((2 * w + ntl) * 4 + ks) * 64 + lane];
            Be[ntl][ks] = Wev[((2 * w + ntl) * 4 + ks) * 64 + lane];
        }

    #pragma unroll
    for (int tl = 0; tl < 2; ++tl) {
        int r = tl * 16 + nl;                        // local row 0..31
        const float* xr = dst_x + (size_t)(d0 + r) * D + quad * 8;
        const float* gr = &g[r * GSTR + quad * 8];
        f32x4 acc[2];
        acc[0] = (f32x4){0.f, 0.f, 0.f, 0.f};
        acc[1] = (f32x4){0.f, 0.f, 0.f, 0.f};
        #pragma unroll
        for (int ks = 0; ks < 4; ++ks) {
            float4 f0 = *(const float4*)(xr + ks * 32);
            float4 f1 = *(const float4*)(xr + ks * 32 + 4);
            float4 g0 = *(const float4*)(gr + ks * 32);
            float4 g1 = *(const float4*)(gr + ks * 32 + 4);
            V8 a1v, a2v;
            a1v.u8[0] = f2bf(f0.x + g0.x); a2v.u8[0] = f2bf(f0.x * g0.x);
            a1v.u8[1] = f2bf(f0.y + g0.y); a2v.u8[1] = f2bf(f0.y * g0.y);
            a1v.u8[2] = f2bf(f0.z + g0.z); a2v.u8[2] = f2bf(f0.z * g0.z);
            a1v.u8[3] = f2bf(f0.w + g0.w); a2v.u8[3] = f2bf(f0.w * g0.w);
            a1v.u8[4] = f2bf(f1.x + g1.x); a2v.u8[4] = f2bf(f1.x * g1.x);
            a1v.u8[5] = f2bf(f1.y + g1.y); a2v.u8[5] = f2bf(f1.y * g1.y);
            a1v.u8[6] = f2bf(f1.z + g1.z); a2v.u8[6] = f2bf(f1.z * g1.z);
            a1v.u8[7] = f2bf(f1.w + g1.w); a2v.u8[7] = f2bf(f1.w * g1.w);
            acc[0] = __builtin_amdgcn_mfma_f32_16x16x32_bf16(a1v.s8, Bi[0][ks], acc[0], 0, 0, 0);
            acc[1] = __builtin_amdgcn_mfma_f32_16x16x32_bf16(a1v.s8, Bi[1][ks], acc[1], 0, 0, 0);
            acc[0] = __builtin_amdgcn_mfma_f32_16x16x32_bf16(a2v.s8, Be[0][ks], acc[0], 0, 0, 0);
            acc[1] = __builtin_amdgcn_mfma_f32_16x16x32_bf16(a2v.s8, Be[1][ks], acc[1], 0, 0, 0);
        }
        // store with fused leaky; C layout as verified
        #pragma unroll
        for (int ntl = 0; ntl < 2; ++ntl)
            #pragma unroll
            for (int rr = 0; rr < 4; ++rr) {
                float v = acc[ntl][rr];
                v = v > 0.f ? v : 0.01f * v;
                out[(size_t)(d0 + tl * 16 + quad * 4 + rr) * D
                    + (2 * w + ntl) * 16 + nl] = v;
            }
    }
}

extern "C" void kernel_launch(void* const* d_in, const int* in_sizes, int n_in,
                              void* d_out, int out_size, void* d_ws, size_t ws_size,
                              hipStream_t stream) {
    const float* src_x = (const float*)d_in[0];
    const float* dst_x = (const float*)d_in[1];
    const int*   eidx  = (const int*)d_in[2];     // [2, E] flat: src then dst
    const float* ew    = (const float*)d_in[3];   // [E, 1]
    const float* Wi    = (const float*)d_in[4];   // [D, D]
    const float* We    = (const float*)d_in[5];   // [D, D]
    float* out = (float*)d_out;

    // ws layout
    char* wsb = (char*)d_ws;
    unsigned short* Wfi = (unsigned short*)(wsb);            // 32768 B
    unsigned short* Wfe = (unsigned short*)(wsb + 32768);    // 32768 B
    unsigned* cur = (unsigned*)(wsb + 65536);                // 16 KB (3125 used)
    int2* bkt = (int2*)(wsb + 65536 + 16384);                // 3125*448*8 = 11.2 MB

    const int* src_idx = eidx;
    const int* dst_idx = eidx + N_EDGES;

    wfrag_kernel<<<16, 256, 0, stream>>>(Wi, We, Wfi, Wfe, cur);

    scatter_kernel<<<(N_EDGES + 255) / 256, 256, 0, stream>>>(
        src_idx, dst_idx, ew, cur, bkt);

    fused_kernel<<<NBUCK, 256, 0, stream>>>(
        src_x, dst_x, bkt, cur, Wfi, Wfe, out);
}

// Round 4
// 261.301 us; speedup vs baseline: 2.3452x; 2.3452x over previous
//
#include <hip/hip_runtime.h>
#include <hip/hip_bf16.h>

#define N_NODES 100000
#define N_EDGES 600000
#define D 128
#define ROWS_PB 32                               // dst rows per fused block
#define NBLK_F (N_NODES / ROWS_PB)               // 3125
#define CAPN 32                                  // per-node bucket capacity (mean deg 6, P(>31)~7e-14)
#define GSTR 132                                 // padded LDS row stride (floats)

typedef __attribute__((ext_vector_type(8))) short short8;
typedef __attribute__((ext_vector_type(8))) unsigned short ushort8;
typedef __attribute__((ext_vector_type(4))) float f32x4;

union V8 { short8 s8; ushort8 u8; };

__device__ __forceinline__ unsigned short f2bf(float f) {
    unsigned u = __float_as_uint(f);
    u += 0x7FFF + ((u >> 16) & 1);   // RNE
    return (unsigned short)(u >> 16);
}

// ---------------- weight fragments + per-node cursor zeroing ----------------
__global__ void wfrag_kernel(const float* __restrict__ Wi,
                             const float* __restrict__ We,
                             unsigned short* __restrict__ Wfi,
                             unsigned short* __restrict__ Wfe,
                             unsigned* __restrict__ cur) {
    int id = blockIdx.x * blockDim.x + threadIdx.x;   // 0..4095
    for (int j = id; j < N_NODES; j += 4096) cur[j] = 0u;   // fold memset in
    int mat = id >> 11;
    int idx = id & 2047;          // nt<<8 | ks<<6 | lane
    int lane = idx & 63;
    int ks = (idx >> 6) & 3;
    int nt = idx >> 8;
    int n = lane & 15, quad = lane >> 4;
    int row = nt * 16 + n;
    int k0 = ks * 32 + quad * 8;
    const float* W = mat ? We : Wi;
    unsigned short* Wf = mat ? Wfe : Wfi;
    #pragma unroll
    for (int j = 0; j < 8; ++j)
        Wf[idx * 8 + j] = f2bf(W[row * D + k0 + j]);
}

// ---------------- one-pass per-node bucket scatter ----------------
// bucket d holds its edges' {src, ew} pairs; within-bucket order irrelevant
// (all edges in a bucket share dst d) -> no sorting needed anywhere.
__global__ void scatter_kernel(const int* __restrict__ src_idx,
                               const int* __restrict__ dst_idx,
                               const float* __restrict__ ew,
                               unsigned* __restrict__ cur,
                               int2* __restrict__ bkt) {
    int i = blockIdx.x * blockDim.x + threadIdx.x;
    if (i < N_EDGES) {
        int s = src_idx[i];
        int d = dst_idx[i];
        float wv = ew[i];
        unsigned pos = atomicAdd(&cur[d], 1u);
        if (pos < CAPN) {
            bkt[(size_t)d * CAPN + pos] = make_int2(s, __float_as_int(wv));
        }
    }
}

// ---------------- fused gather-sum + dual GEMM + leaky ----------------
// out = leaky( (dst_x + g) @ Wi^T + (dst_x .* g) @ We^T ),
// g[d] = sum_{e: dst=d} ew_e * src_x[src_e]  (exact f32).
// Gather: each quad (16 lanes) owns 2 whole dst nodes; accumulates each
// node's g-row in registers (no atomics, no sort), 1-deep row prefetch,
// then ONE plain float4 LDS store per row half. Every g row is written
// unconditionally -> no zero-init, single barrier.
// MFMA phase: W fragments loaded after gather; two 16-row tiles; leaky
// fused; out stored exactly once. (Phase verified in rounds 1-2.)
__global__ __launch_bounds__(256, 4) void fused_kernel(
    const float* __restrict__ src_x,
    const float* __restrict__ dst_x,
    const int2* __restrict__ bkt,
    const unsigned* __restrict__ cur,
    const unsigned short* __restrict__ Wfi,
    const unsigned short* __restrict__ Wfe,
    float* __restrict__ out) {
    __shared__ float g[ROWS_PB * GSTR];   // 32 x 132 f32 = 16.9 KB

    int t = threadIdx.x, lane = t & 63, w = t >> 6;
    int quad = lane >> 4, nl = lane & 15;
    int qid = t >> 4;                      // 0..15

    int b = blockIdx.x, d0 = b * ROWS_PB;

    // ---- gather: quad qid owns local rows 2*qid and 2*qid+1 ----
    #pragma unroll
    for (int half = 0; half < 2; ++half) {
        int r = 2 * qid + half;            // local row 0..31
        int node = d0 + r;
        int cn = (int)cur[node];
        if (cn > CAPN) cn = CAPN;
        const int2* bp = bkt + (size_t)node * CAPN;
        float4 a = {0.f, 0.f, 0.f, 0.f}, c = {0.f, 0.f, 0.f, 0.f};
        if (cn > 0) {
            int2 m0 = bp[0];
            const float* p0 = src_x + (size_t)m0.x * D + nl * 8;
            float4 A0 = *(const float4*)p0, B0 = *(const float4*)(p0 + 4);
            for (int e = 0; e < cn; ++e) {
                int en = (e + 1 < cn) ? e + 1 : cn - 1;
                int2 m1 = bp[en];
                const float* p1 = src_x + (size_t)m1.x * D + nl * 8;
                float4 A1 = *(const float4*)p1, B1 = *(const float4*)(p1 + 4);
                float wgt = __int_as_float(m0.y);
                a.x += wgt * A0.x; a.y += wgt * A0.y;
                a.z += wgt * A0.z; a.w += wgt * A0.w;
                c.x += wgt * B0.x; c.y += wgt * B0.y;
                c.z += wgt * B0.z; c.w += wgt * B0.w;
                m0 = m1; A0 = A1; B0 = B1;
            }
        }
        float* gp = &g[r * GSTR + nl * 8];
        *(float4*)gp = a;                  // plain stores: quad owns the row
        *(float4*)(gp + 4) = c;
    }
    __syncthreads();

    // ---- MFMA phase: W fragments (compiler sinks loads here) ----
    const short8* Wiv = (const short8*)Wfi;
    const short8* Wev = (const short8*)Wfe;
    short8 Bi[2][4], Be[2][4];
    #pragma unroll
    for (int ntl = 0; ntl < 2; ++ntl)
        #pragma unroll
        for (int ks = 0; ks < 4; ++ks) {
            Bi[ntl][ks] = Wiv[((2 * w + ntl) * 4 + ks) * 64 + lane];
            Be[ntl][ks] = Wev[((2 * w + ntl) * 4 + ks) * 64 + lane];
        }

    #pragma unroll
    for (int tl = 0; tl < 2; ++tl) {
        int r = tl * 16 + nl;                        // local row 0..31
        const float* xr = dst_x + (size_t)(d0 + r) * D + quad * 8;
        const float* gr = &g[r * GSTR + quad * 8];
        f32x4 acc[2];
        acc[0] = (f32x4){0.f, 0.f, 0.f, 0.f};
        acc[1] = (f32x4){0.f, 0.f, 0.f, 0.f};
        #pragma unroll
        for (int ks = 0; ks < 4; ++ks) {
            float4 f0 = *(const float4*)(xr + ks * 32);
            float4 f1 = *(const float4*)(xr + ks * 32 + 4);
            float4 g0 = *(const float4*)(gr + ks * 32);
            float4 g1 = *(const float4*)(gr + ks * 32 + 4);
            V8 a1v, a2v;
            a1v.u8[0] = f2bf(f0.x + g0.x); a2v.u8[0] = f2bf(f0.x * g0.x);
            a1v.u8[1] = f2bf(f0.y + g0.y); a2v.u8[1] = f2bf(f0.y * g0.y);
            a1v.u8[2] = f2bf(f0.z + g0.z); a2v.u8[2] = f2bf(f0.z * g0.z);
            a1v.u8[3] = f2bf(f0.w + g0.w); a2v.u8[3] = f2bf(f0.w * g0.w);
            a1v.u8[4] = f2bf(f1.x + g1.x); a2v.u8[4] = f2bf(f1.x * g1.x);
            a1v.u8[5] = f2bf(f1.y + g1.y); a2v.u8[5] = f2bf(f1.y * g1.y);
            a1v.u8[6] = f2bf(f1.z + g1.z); a2v.u8[6] = f2bf(f1.z * g1.z);
            a1v.u8[7] = f2bf(f1.w + g1.w); a2v.u8[7] = f2bf(f1.w * g1.w);
            acc[0] = __builtin_amdgcn_mfma_f32_16x16x32_bf16(a1v.s8, Bi[0][ks], acc[0], 0, 0, 0);
            acc[1] = __builtin_amdgcn_mfma_f32_16x16x32_bf16(a1v.s8, Bi[1][ks], acc[1], 0, 0, 0);
            acc[0] = __builtin_amdgcn_mfma_f32_16x16x32_bf16(a2v.s8, Be[0][ks], acc[0], 0, 0, 0);
            acc[1] = __builtin_amdgcn_mfma_f32_16x16x32_bf16(a2v.s8, Be[1][ks], acc[1], 0, 0, 0);
        }
        // store with fused leaky; C layout as verified
        #pragma unroll
        for (int ntl = 0; ntl < 2; ++ntl)
            #pragma unroll
            for (int rr = 0; rr < 4; ++rr) {
                float v = acc[ntl][rr];
                v = v > 0.f ? v : 0.01f * v;
                out[(size_t)(d0 + tl * 16 + quad * 4 + rr) * D
                    + (2 * w + ntl) * 16 + nl] = v;
            }
    }
}

extern "C" void kernel_launch(void* const* d_in, const int* in_sizes, int n_in,
                              void* d_out, int out_size, void* d_ws, size_t ws_size,
                              hipStream_t stream) {
    const float* src_x = (const float*)d_in[0];
    const float* dst_x = (const float*)d_in[1];
    const int*   eidx  = (const int*)d_in[2];     // [2, E] flat: src then dst
    const float* ew    = (const float*)d_in[3];   // [E, 1]
    const float* Wi    = (const float*)d_in[4];   // [D, D]
    const float* We    = (const float*)d_in[5];   // [D, D]
    float* out = (float*)d_out;

    // ws layout
    char* wsb = (char*)d_ws;
    unsigned short* Wfi = (unsigned short*)(wsb);            // 32768 B
    unsigned short* Wfe = (unsigned short*)(wsb + 32768);    // 32768 B
    unsigned* cur = (unsigned*)(wsb + 65536);                // 400000 B
    int2* bkt = (int2*)(wsb + 65536 + 400000);               // 100000*32*8 = 25.6 MB

    const int* src_idx = eidx;
    const int* dst_idx = eidx + N_EDGES;

    wfrag_kernel<<<16, 256, 0, stream>>>(Wi, We, Wfi, Wfe, cur);

    scatter_kernel<<<(N_EDGES + 255) / 256, 256, 0, stream>>>(
        src_idx, dst_idx, ew, cur, bkt);

    fused_kernel<<<NBLK_F, 256, 0, stream>>>(
        src_x, dst_x, bkt, cur, Wfi, Wfe, out);
}